// Round 4
// baseline (865.957 us; speedup 1.0000x reference)
//
#include <hip/hip_runtime.h>
#include <cstddef>

#define NNODE 10000
#define IND 512
#define HD 256
#define PAD_M 10112   // 79 * 128
#define NTILE 79      // PAD_M / 128
#define NTRI (NTILE * (NTILE + 1) / 2)   // 3160 lower-triangle blocks

typedef __attribute__((ext_vector_type(8))) short short8;
typedef __attribute__((ext_vector_type(4))) float floatx4;

#define GLOAD_LDS16(gp, lp) __builtin_amdgcn_global_load_lds( \
    (const __attribute__((address_space(1))) unsigned int*)(gp), \
    (__attribute__((address_space(3))) unsigned int*)(lp), 16, 0, 0)

// ---------------------------------------------------------------------------
// 1. count degrees (src side for dinv, dst side for CSR rows)
// ---------------------------------------------------------------------------
__global__ void count_kernel(const int* __restrict__ src, const int* __restrict__ dst,
                             int E, int* __restrict__ cnt_src, int* __restrict__ cnt_dst) {
    int e = blockIdx.x * blockDim.x + threadIdx.x;
    if (e < E) {
        atomicAdd(&cnt_src[src[e]], 1);
        atomicAdd(&cnt_dst[dst[e]], 1);
    }
}

// ---------------------------------------------------------------------------
// 2. dinv + exclusive scan of cnt_dst -> row_ptr (single block, 1024 threads)
// ---------------------------------------------------------------------------
__global__ __launch_bounds__(1024) void scan_kernel(const int* __restrict__ cnt_src,
                                                    const int* __restrict__ cnt_dst,
                                                    float* __restrict__ dinv,
                                                    int* __restrict__ row_ptr) {
    int t = threadIdx.x;
    for (int i = t; i < NNODE; i += 1024)
        dinv[i] = rsqrtf(fmaxf((float)cnt_src[i], 1.0f));

    __shared__ int sums[1024];
    const int CH = (NNODE + 1023) / 1024;  // 10
    int base = t * CH;
    int s = 0;
    for (int i = 0; i < CH; ++i) {
        int idx = base + i;
        if (idx < NNODE) s += cnt_dst[idx];
    }
    sums[t] = s;
    __syncthreads();
    for (int off = 1; off < 1024; off <<= 1) {
        int v = (t >= off) ? sums[t - off] : 0;
        __syncthreads();
        sums[t] += v;
        __syncthreads();
    }
    int run = (t == 0) ? 0 : sums[t - 1];
    for (int i = 0; i < CH; ++i) {
        int idx = base + i;
        if (idx < NNODE) { row_ptr[idx] = run; run += cnt_dst[idx]; }
    }
    if (t == 1023) row_ptr[NNODE] = sums[1023];
}

// ---------------------------------------------------------------------------
// 3. fill CSR (by dst): col[] holds src of each edge
// ---------------------------------------------------------------------------
__global__ void fill_kernel(const int* __restrict__ src, const int* __restrict__ dst,
                            int E, const int* __restrict__ row_ptr,
                            int* __restrict__ cursor, int* __restrict__ col) {
    int e = blockIdx.x * blockDim.x + threadIdx.x;
    if (e < E) {
        int v = dst[e];
        int pos = row_ptr[v] + atomicAdd(&cursor[v], 1);
        col[pos] = src[e];
    }
}

// ---------------------------------------------------------------------------
// 4. combine weights w_k = sum_i c_i * THETA[i][k], c = sigmoids of lam
// ---------------------------------------------------------------------------
__global__ void w_kernel(const float* __restrict__ lam, float* __restrict__ w) {
    if (threadIdx.x == 0 && blockIdx.x == 0) {
        float c[5];
        float s0 = 1.0f / (1.0f + expf(-lam[0]));
        c[0] = s0;
        c[1] = s0;  // reference reuses lam[0] for all_h[1]
        c[2] = 1.0f / (1.0f + expf(-lam[1]));
        c[3] = 1.0f / (1.0f + expf(-lam[2]));
        c[4] = 1.0f / (1.0f + expf(-lam[3]));
        const float TH[5][5] = {
            {5.0f, -10.0f,  7.5f, -2.5f, 0.3125f},
            {0.0f,  10.0f, -15.0f, 7.5f, -1.25f },
            {0.0f,   0.0f,  7.5f, -7.5f, 1.875f },
            {0.0f,   0.0f,  0.0f,  2.5f, -1.25f },
            {0.0f,   0.0f,  0.0f,  0.0f, 0.3125f}};
        for (int k = 0; k < 5; ++k) {
            float acc = 0.0f;
            for (int i = 0; i < 5; ++i) acc += c[i] * TH[i][k];
            w[k] = acc;
        }
    }
}

// ---------------------------------------------------------------------------
// 5. GEMM1: h = leaky_relu(in_feat @ W + b); f_a = h; recons = w0 * h
// ---------------------------------------------------------------------------
__global__ __launch_bounds__(256) void gemm1_kernel(
    const float* __restrict__ A,   // NNODE x IND
    const float* __restrict__ W,   // IND x HD
    const float* __restrict__ bias,
    const float* __restrict__ w5,
    float* __restrict__ h_out,     // NNODE x HD
    float* __restrict__ recons) {
    const int m0 = blockIdx.x * 64, n0 = blockIdx.y * 64;
    __shared__ float As[16][64];
    __shared__ float Bs[16][64];
    const int t = threadIdx.x;
    const int tm = t >> 4, tn = t & 15;
    float acc[4][4] = {};
    for (int k0 = 0; k0 < IND; k0 += 16) {
        {
            int m = t >> 2, kq = t & 3;
            int row = m0 + m;
            float4 v = make_float4(0.f, 0.f, 0.f, 0.f);
            if (row < NNODE) v = *(const float4*)(A + (size_t)row * IND + k0 + 4 * kq);
            As[4 * kq + 0][m] = v.x;
            As[4 * kq + 1][m] = v.y;
            As[4 * kq + 2][m] = v.z;
            As[4 * kq + 3][m] = v.w;
        }
        {
            int kk = t >> 4, nq = t & 15;
            float4 v = *(const float4*)(W + (size_t)(k0 + kk) * HD + n0 + 4 * nq);
            *(float4*)&Bs[kk][4 * nq] = v;
        }
        __syncthreads();
#pragma unroll
        for (int kk = 0; kk < 16; ++kk) {
            float4 av = *(const float4*)&As[kk][tm * 4];
            float4 bv = *(const float4*)&Bs[kk][tn * 4];
            float a[4] = {av.x, av.y, av.z, av.w};
            float b[4] = {bv.x, bv.y, bv.z, bv.w};
#pragma unroll
            for (int i = 0; i < 4; ++i)
#pragma unroll
                for (int j = 0; j < 4; ++j)
                    acc[i][j] = fmaf(a[i], b[j], acc[i][j]);
        }
        __syncthreads();
    }
    float w0 = w5[0];
#pragma unroll
    for (int i = 0; i < 4; ++i) {
        int row = m0 + tm * 4 + i;
        if (row >= NNODE) break;
#pragma unroll
        for (int j = 0; j < 4; ++j) {
            int cc = n0 + tn * 4 + j;
            float v = acc[i][j] + bias[cc];
            v = v > 0.0f ? v : 0.01f * v;
            h_out[(size_t)row * HD + cc] = v;
            recons[(size_t)row * HD + cc] = w0 * v;
        }
    }
}

// ---------------------------------------------------------------------------
// 6. Laplacian step (gather form) + recons accumulation (k = 1..3)
// ---------------------------------------------------------------------------
__global__ __launch_bounds__(256) void lap_kernel(
    const float* __restrict__ fin, float* __restrict__ fout,
    float* __restrict__ recons, const float* __restrict__ dinv,
    const int* __restrict__ row_ptr, const int* __restrict__ col,
    const float* __restrict__ w5, int k) {
    const int v = blockIdx.x;
    const int c = threadIdx.x;
    const int beg = row_ptr[v], end = row_ptr[v + 1];
    float s = 0.0f;
    for (int j = beg; j < end; ++j) {
        int u = col[j];
        s = fmaf(fin[(size_t)u * HD + c], dinv[u], s);
    }
    float o = fin[(size_t)v * HD + c] - dinv[v] * s;
    fout[(size_t)v * HD + c] = o;
    recons[(size_t)v * HD + c] += w5[k] * o;
}

// ---------------------------------------------------------------------------
// 6b. last Laplacian step fused with bf16 hi/lo split of the final recons
// ---------------------------------------------------------------------------
__global__ __launch_bounds__(256) void lap_last_kernel(
    const float* __restrict__ fin, const float* __restrict__ recons,
    const float* __restrict__ dinv,
    const int* __restrict__ row_ptr, const int* __restrict__ col,
    const float* __restrict__ w5,
    unsigned short* __restrict__ Rhi, unsigned short* __restrict__ Rlo) {
    const int v = blockIdx.x;
    const int c = threadIdx.x;
    const int beg = row_ptr[v], end = row_ptr[v + 1];
    float s = 0.0f;
    for (int j = beg; j < end; ++j) {
        int u = col[j];
        s = fmaf(fin[(size_t)u * HD + c], dinv[u], s);
    }
    float o = fin[(size_t)v * HD + c] - dinv[v] * s;
    float r = recons[(size_t)v * HD + c] + w5[4] * o;
    unsigned u = __float_as_uint(r);
    float hif = __uint_as_float(u & 0xFFFF0000u);
    float lof = r - hif;   // exact (same binade)
    Rhi[(size_t)v * HD + c] = (unsigned short)(u >> 16);
    Rlo[(size_t)v * HD + c] = (unsigned short)(__float_as_uint(lof) >> 16);
}

// ---------------------------------------------------------------------------
// 7. GEMM2 (MFMA): out = sigmoid(R R^T) via Hi Hi^T + Hi Lo^T + Lo Hi^T
//    Lower-triangle blocks only (output is symmetric); mirror tile written
//    through an LDS transpose so both writes are row-coalesced. All output
//    stores are non-temporal so the 400 MB stream doesn't evict the panels.
// ---------------------------------------------------------------------------
__global__ __launch_bounds__(256) void gemm2_mfma(
    const unsigned short* __restrict__ Rhi,
    const unsigned short* __restrict__ Rlo,
    float* __restrict__ out) {
    __shared__ __align__(16) char smem[32768];
    unsigned short (*As)[64] = (unsigned short (*)[64])smem;
    unsigned short (*Bs)[64] = (unsigned short (*)[64])(smem + 16384);
    float (*trs)[129] = (float (*)[129])smem;   // [32][129] fp32, 16.5 KB

    // triangular decode: block k -> (bi, bj), bi >= bj
    int kb = blockIdx.x;
    int bi = (int)((sqrtf(8.0f * (float)kb + 1.0f) - 1.0f) * 0.5f);
    while ((bi + 1) * (bi + 2) / 2 <= kb) ++bi;
    while (bi * (bi + 1) / 2 > kb) --bi;
    int bj = kb - bi * (bi + 1) / 2;
    const int brow = bi * 128, bcol = bj * 128;

    const int t = threadIdx.x;
    const int lane = t & 63;
    const int wave = t >> 6;
    const int wm = wave >> 1, wn = wave & 1;
    const int fr = lane & 15;
    const int kq = lane >> 4;   // k-quarter (and C-row group)

    floatx4 acc[4][4];
#pragma unroll
    for (int i = 0; i < 4; ++i)
#pragma unroll
        for (int j = 0; j < 4; ++j)
            acc[i][j] = (floatx4){0.f, 0.f, 0.f, 0.f};

    const int srow = t >> 3;           // 0..31
    const int scol = (t & 7) * 8;      // 0..56

    for (int ks = 0; ks < 12; ++ks) {
        const int seg = ks >> 2;
        const int k0 = (ks & 3) * 64;
        const unsigned short* Aseg = (seg < 2) ? Rhi : Rlo;
        const unsigned short* Bseg = (seg == 1) ? Rlo : Rhi;
#pragma unroll
        for (int q = 0; q < 4; ++q) {
            const unsigned short* ga = Aseg + (size_t)(brow + q * 32 + srow) * HD + k0 + scol;
            const unsigned short* gb = Bseg + (size_t)(bcol + q * 32 + srow) * HD + k0 + scol;
            GLOAD_LDS16(ga, (unsigned short*)smem + q * 2048 + t * 8);
            GLOAD_LDS16(gb, (unsigned short*)smem + 8192 + q * 2048 + t * 8);
        }
        __syncthreads();
#pragma unroll
        for (int kk = 0; kk < 2; ++kk) {
            short8 a[4], b[4];
#pragma unroll
            for (int i = 0; i < 4; ++i)
                a[i] = *(const short8*)&As[wm * 64 + i * 16 + fr][kk * 32 + kq * 8];
#pragma unroll
            for (int j = 0; j < 4; ++j)
                b[j] = *(const short8*)&Bs[wn * 64 + j * 16 + fr][kk * 32 + kq * 8];
#pragma unroll
            for (int i = 0; i < 4; ++i)
#pragma unroll
                for (int j = 0; j < 4; ++j)
                    acc[i][j] = __builtin_amdgcn_mfma_f32_16x16x32_bf16(
                        a[i], b[j], acc[i][j], 0, 0, 0);
        }
        __syncthreads();
    }

    // --- direct tile write: C/D layout col=lane&15, row=(lane>>4)*4+reg ---
#pragma unroll
    for (int i = 0; i < 4; ++i) {
#pragma unroll
        for (int j = 0; j < 4; ++j) {
            int gcol = bcol + wn * 64 + j * 16 + fr;
#pragma unroll
            for (int r = 0; r < 4; ++r) {
                int grow = brow + wm * 64 + i * 16 + kq * 4 + r;
                if (grow < NNODE && gcol < NNODE) {
                    float s = 1.0f / (1.0f + __expf(-acc[i][j][r]));
                    __builtin_nontemporal_store(s, &out[(size_t)grow * NNODE + gcol]);
                }
            }
        }
    }

    // --- mirror tile via LDS transpose (skip diagonal: it's symmetric) ---
    if (bi == bj) return;
    const int cmax = NNODE - brow;   // valid mirror cols (>=128 except last bi)
    for (int c0 = 0; c0 < 128; c0 += 32) {
        __syncthreads();   // LDS free (K-loop done / previous chunk consumed)
        if (wn == (c0 >> 6)) {
            int cbase = c0 & 63;
            int jlo = cbase >> 4;
#pragma unroll
            for (int jj = 0; jj < 2; ++jj) {
                int j = jlo + jj;
                int tc = fr + jj * 16;          // 0..31 within chunk
#pragma unroll
                for (int i = 0; i < 4; ++i)
#pragma unroll
                    for (int r = 0; r < 4; ++r) {
                        float s = 1.0f / (1.0f + __expf(-acc[i][j][r]));
                        trs[tc][wm * 64 + i * 16 + kq * 4 + r] = s;
                    }
            }
        }
        __syncthreads();
        // cooperative coalesced write of 32 mirror rows x 128 cols
        int tr = t >> 3;
        int x0 = (t & 7) * 16;
        int gr = bcol + c0 + tr;
        if (gr < NNODE) {
            float* orow = out + (size_t)gr * NNODE + brow;
            if (x0 + 16 <= cmax) {
#pragma unroll
                for (int x = 0; x < 16; x += 4) {
                    floatx4 v;
                    v[0] = trs[tr][x0 + x + 0];
                    v[1] = trs[tr][x0 + x + 1];
                    v[2] = trs[tr][x0 + x + 2];
                    v[3] = trs[tr][x0 + x + 3];
                    __builtin_nontemporal_store(v, (floatx4*)(orow + x0 + x));
                }
            } else {
                for (int x = x0; x < x0 + 16 && x < cmax; ++x)
                    __builtin_nontemporal_store(trs[tr][x], orow + x);
            }
        }
    }
}

// ---------------------------------------------------------------------------
extern "C" void kernel_launch(void* const* d_in, const int* in_sizes, int n_in,
                              void* d_out, int out_size, void* d_ws, size_t ws_size,
                              hipStream_t stream) {
    const float* in_feat = (const float*)d_in[0];
    const float* W       = (const float*)d_in[1];
    const float* bias    = (const float*)d_in[2];
    const float* lam     = (const float*)d_in[3];
    const int*   src     = (const int*)d_in[4];
    const int*   dst     = (const int*)d_in[5];
    const int    E       = in_sizes[4];
    float* out = (float*)d_out;

    char* p = (char*)d_ws;
    auto alloc = [&](size_t bytes) -> void* {
        void* r = (void*)p;
        p += (bytes + 255) & ~(size_t)255;
        return r;
    };
    int*   cnts    = (int*)alloc(3 * NNODE * sizeof(int));
    int*   cnt_src = cnts;
    int*   cnt_dst = cnts + NNODE;
    int*   cursor  = cnts + 2 * NNODE;
    int*   row_ptr = (int*)alloc((NNODE + 1) * sizeof(int));
    int*   col     = (int*)alloc((size_t)E * sizeof(int));
    float* dinv    = (float*)alloc(NNODE * sizeof(float));
    float* w5      = (float*)alloc(8 * sizeof(float));
    float* f_a     = (float*)alloc((size_t)NNODE * HD * sizeof(float));
    float* f_b     = (float*)alloc((size_t)NNODE * HD * sizeof(float));
    float* recons  = (float*)alloc((size_t)NNODE * HD * sizeof(float));
    unsigned short* Rhi = (unsigned short*)alloc((size_t)PAD_M * HD * sizeof(unsigned short));
    unsigned short* Rlo = (unsigned short*)alloc((size_t)PAD_M * HD * sizeof(unsigned short));

    hipMemsetAsync(cnts, 0, 3 * NNODE * sizeof(int), stream);
    hipMemsetAsync(Rhi + (size_t)NNODE * HD, 0, (size_t)(PAD_M - NNODE) * HD * 2, stream);
    hipMemsetAsync(Rlo + (size_t)NNODE * HD, 0, (size_t)(PAD_M - NNODE) * HD * 2, stream);

    int eb = (E + 255) / 256;
    count_kernel<<<eb, 256, 0, stream>>>(src, dst, E, cnt_src, cnt_dst);
    w_kernel<<<1, 64, 0, stream>>>(lam, w5);
    scan_kernel<<<1, 1024, 0, stream>>>(cnt_src, cnt_dst, dinv, row_ptr);
    fill_kernel<<<eb, 256, 0, stream>>>(src, dst, E, row_ptr, cursor, col);

    dim3 g1((NNODE + 63) / 64, HD / 64);
    gemm1_kernel<<<g1, 256, 0, stream>>>(in_feat, W, bias, w5, f_a, recons);

    lap_kernel<<<NNODE, 256, 0, stream>>>(f_a, f_b, recons, dinv, row_ptr, col, w5, 1);
    lap_kernel<<<NNODE, 256, 0, stream>>>(f_b, f_a, recons, dinv, row_ptr, col, w5, 2);
    lap_kernel<<<NNODE, 256, 0, stream>>>(f_a, f_b, recons, dinv, row_ptr, col, w5, 3);
    lap_last_kernel<<<NNODE, 256, 0, stream>>>(f_b, recons, dinv, row_ptr, col, w5, Rhi, Rlo);

    gemm2_mfma<<<NTRI, 256, 0, stream>>>(Rhi, Rlo, out);
}

// Round 5
// 608.388 us; speedup vs baseline: 1.4234x; 1.4234x over previous
//
#include <hip/hip_runtime.h>
#include <cstddef>

#define NNODE 10000
#define IND 512
#define HD 256
#define PAD_M 10112   // 79 * 128
#define NTILE 79      // PAD_M / 128
#define NTRI (NTILE * (NTILE + 1) / 2)   // 3160 lower-triangle blocks

typedef __attribute__((ext_vector_type(8))) short short8;
typedef __attribute__((ext_vector_type(4))) float floatx4;

#define GLOAD_LDS16(gp, lp) __builtin_amdgcn_global_load_lds( \
    (const __attribute__((address_space(1))) unsigned int*)(gp), \
    (__attribute__((address_space(3))) unsigned int*)(lp), 16, 0, 0)

// ---------------------------------------------------------------------------
// 1. count degrees (src side for dinv, dst side for CSR rows)
// ---------------------------------------------------------------------------
__global__ void count_kernel(const int* __restrict__ src, const int* __restrict__ dst,
                             int E, int* __restrict__ cnt_src, int* __restrict__ cnt_dst) {
    int e = blockIdx.x * blockDim.x + threadIdx.x;
    if (e < E) {
        atomicAdd(&cnt_src[src[e]], 1);
        atomicAdd(&cnt_dst[dst[e]], 1);
    }
}

// ---------------------------------------------------------------------------
// 2. dinv + exclusive scan of cnt_dst -> row_ptr (single block, 1024 threads)
// ---------------------------------------------------------------------------
__global__ __launch_bounds__(1024) void scan_kernel(const int* __restrict__ cnt_src,
                                                    const int* __restrict__ cnt_dst,
                                                    float* __restrict__ dinv,
                                                    int* __restrict__ row_ptr) {
    int t = threadIdx.x;
    for (int i = t; i < NNODE; i += 1024)
        dinv[i] = rsqrtf(fmaxf((float)cnt_src[i], 1.0f));

    __shared__ int sums[1024];
    const int CH = (NNODE + 1023) / 1024;  // 10
    int base = t * CH;
    int s = 0;
    for (int i = 0; i < CH; ++i) {
        int idx = base + i;
        if (idx < NNODE) s += cnt_dst[idx];
    }
    sums[t] = s;
    __syncthreads();
    for (int off = 1; off < 1024; off <<= 1) {
        int v = (t >= off) ? sums[t - off] : 0;
        __syncthreads();
        sums[t] += v;
        __syncthreads();
    }
    int run = (t == 0) ? 0 : sums[t - 1];
    for (int i = 0; i < CH; ++i) {
        int idx = base + i;
        if (idx < NNODE) { row_ptr[idx] = run; run += cnt_dst[idx]; }
    }
    if (t == 1023) row_ptr[NNODE] = sums[1023];
}

// ---------------------------------------------------------------------------
// 3. fill CSR (by dst): col[] holds src of each edge
// ---------------------------------------------------------------------------
__global__ void fill_kernel(const int* __restrict__ src, const int* __restrict__ dst,
                            int E, const int* __restrict__ row_ptr,
                            int* __restrict__ cursor, int* __restrict__ col) {
    int e = blockIdx.x * blockDim.x + threadIdx.x;
    if (e < E) {
        int v = dst[e];
        int pos = row_ptr[v] + atomicAdd(&cursor[v], 1);
        col[pos] = src[e];
    }
}

// ---------------------------------------------------------------------------
// 4. combine weights w_k = sum_i c_i * THETA[i][k], c = sigmoids of lam
// ---------------------------------------------------------------------------
__global__ void w_kernel(const float* __restrict__ lam, float* __restrict__ w) {
    if (threadIdx.x == 0 && blockIdx.x == 0) {
        float c[5];
        float s0 = 1.0f / (1.0f + expf(-lam[0]));
        c[0] = s0;
        c[1] = s0;  // reference reuses lam[0] for all_h[1]
        c[2] = 1.0f / (1.0f + expf(-lam[1]));
        c[3] = 1.0f / (1.0f + expf(-lam[2]));
        c[4] = 1.0f / (1.0f + expf(-lam[3]));
        const float TH[5][5] = {
            {5.0f, -10.0f,  7.5f, -2.5f, 0.3125f},
            {0.0f,  10.0f, -15.0f, 7.5f, -1.25f },
            {0.0f,   0.0f,  7.5f, -7.5f, 1.875f },
            {0.0f,   0.0f,  0.0f,  2.5f, -1.25f },
            {0.0f,   0.0f,  0.0f,  0.0f, 0.3125f}};
        for (int k = 0; k < 5; ++k) {
            float acc = 0.0f;
            for (int i = 0; i < 5; ++i) acc += c[i] * TH[i][k];
            w[k] = acc;
        }
    }
}

// ---------------------------------------------------------------------------
// 5. GEMM1: h = leaky_relu(in_feat @ W + b); f_a = h; recons = w0 * h
// ---------------------------------------------------------------------------
__global__ __launch_bounds__(256) void gemm1_kernel(
    const float* __restrict__ A,   // NNODE x IND
    const float* __restrict__ W,   // IND x HD
    const float* __restrict__ bias,
    const float* __restrict__ w5,
    float* __restrict__ h_out,     // NNODE x HD
    float* __restrict__ recons) {
    const int m0 = blockIdx.x * 64, n0 = blockIdx.y * 64;
    __shared__ float As[16][64];
    __shared__ float Bs[16][64];
    const int t = threadIdx.x;
    const int tm = t >> 4, tn = t & 15;
    float acc[4][4] = {};
    for (int k0 = 0; k0 < IND; k0 += 16) {
        {
            int m = t >> 2, kq = t & 3;
            int row = m0 + m;
            float4 v = make_float4(0.f, 0.f, 0.f, 0.f);
            if (row < NNODE) v = *(const float4*)(A + (size_t)row * IND + k0 + 4 * kq);
            As[4 * kq + 0][m] = v.x;
            As[4 * kq + 1][m] = v.y;
            As[4 * kq + 2][m] = v.z;
            As[4 * kq + 3][m] = v.w;
        }
        {
            int kk = t >> 4, nq = t & 15;
            float4 v = *(const float4*)(W + (size_t)(k0 + kk) * HD + n0 + 4 * nq);
            *(float4*)&Bs[kk][4 * nq] = v;
        }
        __syncthreads();
#pragma unroll
        for (int kk = 0; kk < 16; ++kk) {
            float4 av = *(const float4*)&As[kk][tm * 4];
            float4 bv = *(const float4*)&Bs[kk][tn * 4];
            float a[4] = {av.x, av.y, av.z, av.w};
            float b[4] = {bv.x, bv.y, bv.z, bv.w};
#pragma unroll
            for (int i = 0; i < 4; ++i)
#pragma unroll
                for (int j = 0; j < 4; ++j)
                    acc[i][j] = fmaf(a[i], b[j], acc[i][j]);
        }
        __syncthreads();
    }
    float w0 = w5[0];
#pragma unroll
    for (int i = 0; i < 4; ++i) {
        int row = m0 + tm * 4 + i;
        if (row >= NNODE) break;
#pragma unroll
        for (int j = 0; j < 4; ++j) {
            int cc = n0 + tn * 4 + j;
            float v = acc[i][j] + bias[cc];
            v = v > 0.0f ? v : 0.01f * v;
            h_out[(size_t)row * HD + cc] = v;
            recons[(size_t)row * HD + cc] = w0 * v;
        }
    }
}

// ---------------------------------------------------------------------------
// 6. Laplacian step (gather form) + recons accumulation (k = 1..3)
// ---------------------------------------------------------------------------
__global__ __launch_bounds__(256) void lap_kernel(
    const float* __restrict__ fin, float* __restrict__ fout,
    float* __restrict__ recons, const float* __restrict__ dinv,
    const int* __restrict__ row_ptr, const int* __restrict__ col,
    const float* __restrict__ w5, int k) {
    const int v = blockIdx.x;
    const int c = threadIdx.x;
    const int beg = row_ptr[v], end = row_ptr[v + 1];
    float s = 0.0f;
    for (int j = beg; j < end; ++j) {
        int u = col[j];
        s = fmaf(fin[(size_t)u * HD + c], dinv[u], s);
    }
    float o = fin[(size_t)v * HD + c] - dinv[v] * s;
    fout[(size_t)v * HD + c] = o;
    recons[(size_t)v * HD + c] += w5[k] * o;
}

// ---------------------------------------------------------------------------
// 6b. last Laplacian step fused with bf16 hi/lo split of the final recons
// ---------------------------------------------------------------------------
__global__ __launch_bounds__(256) void lap_last_kernel(
    const float* __restrict__ fin, const float* __restrict__ recons,
    const float* __restrict__ dinv,
    const int* __restrict__ row_ptr, const int* __restrict__ col,
    const float* __restrict__ w5,
    unsigned short* __restrict__ Rhi, unsigned short* __restrict__ Rlo) {
    const int v = blockIdx.x;
    const int c = threadIdx.x;
    const int beg = row_ptr[v], end = row_ptr[v + 1];
    float s = 0.0f;
    for (int j = beg; j < end; ++j) {
        int u = col[j];
        s = fmaf(fin[(size_t)u * HD + c], dinv[u], s);
    }
    float o = fin[(size_t)v * HD + c] - dinv[v] * s;
    float r = recons[(size_t)v * HD + c] + w5[4] * o;
    unsigned u = __float_as_uint(r);
    float hif = __uint_as_float(u & 0xFFFF0000u);
    float lof = r - hif;   // exact (same binade)
    Rhi[(size_t)v * HD + c] = (unsigned short)(u >> 16);
    Rlo[(size_t)v * HD + c] = (unsigned short)(__float_as_uint(lof) >> 16);
}

// ---------------------------------------------------------------------------
// 7. GEMM2 (MFMA): out = sigmoid(R R^T) via Hi Hi^T + Hi Lo^T + Lo Hi^T
//    Lower-triangle blocks only; BOTH tile writes staged through LDS so every
//    NT store instruction covers full 128B lines (lane tl writes float4 at
//    col tl*4 + k*32 -> 8 lanes = one full line). Avoids the R4 partial-line
//    NT write amplification (WRITE 768 MB -> ~405 MB).
// ---------------------------------------------------------------------------
__global__ __launch_bounds__(256) void gemm2_mfma(
    const unsigned short* __restrict__ Rhi,
    const unsigned short* __restrict__ Rlo,
    float* __restrict__ out) {
    __shared__ __align__(16) char smem[32768];
    unsigned short (*As)[64] = (unsigned short (*)[64])smem;
    unsigned short (*Bs)[64] = (unsigned short (*)[64])(smem + 16384);

    // triangular decode: block k -> (bi, bj), bi >= bj
    int kb = blockIdx.x;
    int bi = (int)((sqrtf(8.0f * (float)kb + 1.0f) - 1.0f) * 0.5f);
    while ((bi + 1) * (bi + 2) / 2 <= kb) ++bi;
    while (bi * (bi + 1) / 2 > kb) --bi;
    int bj = kb - bi * (bi + 1) / 2;
    const int brow = bi * 128, bcol = bj * 128;

    const int t = threadIdx.x;
    const int lane = t & 63;
    const int wave = t >> 6;
    const int wm = wave >> 1, wn = wave & 1;
    const int fr = lane & 15;
    const int kq = lane >> 4;   // k-quarter (and C-row group)

    floatx4 acc[4][4];
#pragma unroll
    for (int i = 0; i < 4; ++i)
#pragma unroll
        for (int j = 0; j < 4; ++j)
            acc[i][j] = (floatx4){0.f, 0.f, 0.f, 0.f};

    const int srow = t >> 3;           // 0..31
    const int scol = (t & 7) * 8;      // 0..56

    for (int ks = 0; ks < 12; ++ks) {
        const int seg = ks >> 2;
        const int k0 = (ks & 3) * 64;
        const unsigned short* Aseg = (seg < 2) ? Rhi : Rlo;
        const unsigned short* Bseg = (seg == 1) ? Rlo : Rhi;
#pragma unroll
        for (int q = 0; q < 4; ++q) {
            const unsigned short* ga = Aseg + (size_t)(brow + q * 32 + srow) * HD + k0 + scol;
            const unsigned short* gb = Bseg + (size_t)(bcol + q * 32 + srow) * HD + k0 + scol;
            GLOAD_LDS16(ga, (unsigned short*)smem + q * 2048 + t * 8);
            GLOAD_LDS16(gb, (unsigned short*)smem + 8192 + q * 2048 + t * 8);
        }
        __syncthreads();
#pragma unroll
        for (int kk = 0; kk < 2; ++kk) {
            short8 a[4], b[4];
#pragma unroll
            for (int i = 0; i < 4; ++i)
                a[i] = *(const short8*)&As[wm * 64 + i * 16 + fr][kk * 32 + kq * 8];
#pragma unroll
            for (int j = 0; j < 4; ++j)
                b[j] = *(const short8*)&Bs[wn * 64 + j * 16 + fr][kk * 32 + kq * 8];
#pragma unroll
            for (int i = 0; i < 4; ++i)
#pragma unroll
                for (int j = 0; j < 4; ++j)
                    acc[i][j] = __builtin_amdgcn_mfma_f32_16x16x32_bf16(
                        a[i], b[j], acc[i][j], 0, 0, 0);
        }
        __syncthreads();
    }

    const int tr = t >> 3, tl = t & 7;

    // --- direct tile: stage 32-row chunks in LDS, full-line NT writes ---
    {
        float (*sd)[132] = (float (*)[132])smem;   // 32*132*4 = 16.9 KB
        const int cmaxd = NNODE - bcol;            // >= 16, multiple of 4
#pragma unroll
        for (int c0 = 0; c0 < 128; c0 += 32) {
            if (wm == (c0 >> 6)) {
                int ibase = (c0 & 63) >> 4;
#pragma unroll
                for (int ii = 0; ii < 2; ++ii) {
                    int i = ibase + ii;
#pragma unroll
                    for (int j = 0; j < 4; ++j)
#pragma unroll
                        for (int r = 0; r < 4; ++r) {
                            float s = 1.0f / (1.0f + __expf(-acc[i][j][r]));
                            sd[ii * 16 + kq * 4 + r][wn * 64 + j * 16 + fr] = s;
                        }
                }
            }
            __syncthreads();
            int grow = brow + c0 + tr;
            if (grow < NNODE) {
                float* orow = out + (size_t)grow * NNODE + bcol;
#pragma unroll
                for (int k = 0; k < 4; ++k) {
                    int x = tl * 4 + k * 32;
                    if (x + 4 <= cmaxd) {
                        floatx4 v = {sd[tr][x], sd[tr][x + 1], sd[tr][x + 2], sd[tr][x + 3]};
                        __builtin_nontemporal_store(v, (floatx4*)(orow + x));
                    } else {
                        for (int xx = x; xx < cmaxd && xx < x + 4; ++xx)
                            __builtin_nontemporal_store(sd[tr][xx], orow + xx);
                    }
                }
            }
            __syncthreads();
        }
    }

    // --- mirror tile via LDS transpose (skip diagonal) ---
    if (bi == bj) return;
    {
        float (*trs)[129] = (float (*)[129])smem;  // 32*129*4 = 16.5 KB
        const int cmax = NNODE - brow;             // >= 16, multiple of 4
#pragma unroll
        for (int c0 = 0; c0 < 128; c0 += 32) {
            if (wn == (c0 >> 6)) {
                int jlo = (c0 & 63) >> 4;
#pragma unroll
                for (int jj = 0; jj < 2; ++jj) {
                    int j = jlo + jj;
#pragma unroll
                    for (int i = 0; i < 4; ++i)
#pragma unroll
                        for (int r = 0; r < 4; ++r) {
                            float s = 1.0f / (1.0f + __expf(-acc[i][j][r]));
                            trs[jj * 16 + fr][wm * 64 + i * 16 + kq * 4 + r] = s;
                        }
                }
            }
            __syncthreads();
            int gr = bcol + c0 + tr;   // always < NNODE (bj < bi)
            float* orow = out + (size_t)gr * NNODE + brow;
#pragma unroll
            for (int k = 0; k < 4; ++k) {
                int x = tl * 4 + k * 32;
                if (x + 4 <= cmax) {
                    floatx4 v = {trs[tr][x], trs[tr][x + 1], trs[tr][x + 2], trs[tr][x + 3]};
                    __builtin_nontemporal_store(v, (floatx4*)(orow + x));
                } else {
                    for (int xx = x; xx < cmax && xx < x + 4; ++xx)
                        __builtin_nontemporal_store(trs[tr][xx], orow + xx);
                }
            }
            __syncthreads();
        }
    }
}

// ---------------------------------------------------------------------------
extern "C" void kernel_launch(void* const* d_in, const int* in_sizes, int n_in,
                              void* d_out, int out_size, void* d_ws, size_t ws_size,
                              hipStream_t stream) {
    const float* in_feat = (const float*)d_in[0];
    const float* W       = (const float*)d_in[1];
    const float* bias    = (const float*)d_in[2];
    const float* lam     = (const float*)d_in[3];
    const int*   src     = (const int*)d_in[4];
    const int*   dst     = (const int*)d_in[5];
    const int    E       = in_sizes[4];
    float* out = (float*)d_out;

    char* p = (char*)d_ws;
    auto alloc = [&](size_t bytes) -> void* {
        void* r = (void*)p;
        p += (bytes + 255) & ~(size_t)255;
        return r;
    };
    int*   cnts    = (int*)alloc(3 * NNODE * sizeof(int));
    int*   cnt_src = cnts;
    int*   cnt_dst = cnts + NNODE;
    int*   cursor  = cnts + 2 * NNODE;
    int*   row_ptr = (int*)alloc((NNODE + 1) * sizeof(int));
    int*   col     = (int*)alloc((size_t)E * sizeof(int));
    float* dinv    = (float*)alloc(NNODE * sizeof(float));
    float* w5      = (float*)alloc(8 * sizeof(float));
    float* f_a     = (float*)alloc((size_t)NNODE * HD * sizeof(float));
    float* f_b     = (float*)alloc((size_t)NNODE * HD * sizeof(float));
    float* recons  = (float*)alloc((size_t)NNODE * HD * sizeof(float));
    unsigned short* Rhi = (unsigned short*)alloc((size_t)PAD_M * HD * sizeof(unsigned short));
    unsigned short* Rlo = (unsigned short*)alloc((size_t)PAD_M * HD * sizeof(unsigned short));

    hipMemsetAsync(cnts, 0, 3 * NNODE * sizeof(int), stream);
    hipMemsetAsync(Rhi + (size_t)NNODE * HD, 0, (size_t)(PAD_M - NNODE) * HD * 2, stream);
    hipMemsetAsync(Rlo + (size_t)NNODE * HD, 0, (size_t)(PAD_M - NNODE) * HD * 2, stream);

    int eb = (E + 255) / 256;
    count_kernel<<<eb, 256, 0, stream>>>(src, dst, E, cnt_src, cnt_dst);
    w_kernel<<<1, 64, 0, stream>>>(lam, w5);
    scan_kernel<<<1, 1024, 0, stream>>>(cnt_src, cnt_dst, dinv, row_ptr);
    fill_kernel<<<eb, 256, 0, stream>>>(src, dst, E, row_ptr, cursor, col);

    dim3 g1((NNODE + 63) / 64, HD / 64);
    gemm1_kernel<<<g1, 256, 0, stream>>>(in_feat, W, bias, w5, f_a, recons);

    lap_kernel<<<NNODE, 256, 0, stream>>>(f_a, f_b, recons, dinv, row_ptr, col, w5, 1);
    lap_kernel<<<NNODE, 256, 0, stream>>>(f_b, f_a, recons, dinv, row_ptr, col, w5, 2);
    lap_kernel<<<NNODE, 256, 0, stream>>>(f_a, f_b, recons, dinv, row_ptr, col, w5, 3);
    lap_last_kernel<<<NNODE, 256, 0, stream>>>(f_b, recons, dinv, row_ptr, col, w5, Rhi, Rlo);

    gemm2_mfma<<<NTRI, 256, 0, stream>>>(Rhi, Rlo, out);
}

// Round 6
// 553.007 us; speedup vs baseline: 1.5659x; 1.1001x over previous
//
#include <hip/hip_runtime.h>
#include <cstddef>

#define NNODE 10000
#define IND 512
#define HD 256
#define PAD_M 10112   // 79 * 128
#define NTILE 79      // PAD_M / 128
#define NTRI (NTILE * (NTILE + 1) / 2)   // 3160 lower-triangle blocks

typedef __attribute__((ext_vector_type(8))) short short8;
typedef __attribute__((ext_vector_type(4))) float floatx4;
typedef __attribute__((ext_vector_type(4))) unsigned short ushortx4;

#define GLOAD_LDS16(gp, lp) __builtin_amdgcn_global_load_lds( \
    (const __attribute__((address_space(1))) unsigned int*)(gp), \
    (__attribute__((address_space(3))) unsigned int*)(lp), 16, 0, 0)

// ---------------------------------------------------------------------------
// 1. count degrees
// ---------------------------------------------------------------------------
__global__ void count_kernel(const int* __restrict__ src, const int* __restrict__ dst,
                             int E, int* __restrict__ cnt_src, int* __restrict__ cnt_dst) {
    int e = blockIdx.x * blockDim.x + threadIdx.x;
    if (e < E) {
        atomicAdd(&cnt_src[src[e]], 1);
        atomicAdd(&cnt_dst[dst[e]], 1);
    }
}

// ---------------------------------------------------------------------------
// 2. dinv + exclusive scan of cnt_dst -> row_ptr
// ---------------------------------------------------------------------------
__global__ __launch_bounds__(1024) void scan_kernel(const int* __restrict__ cnt_src,
                                                    const int* __restrict__ cnt_dst,
                                                    float* __restrict__ dinv,
                                                    int* __restrict__ row_ptr) {
    int t = threadIdx.x;
    for (int i = t; i < NNODE; i += 1024)
        dinv[i] = rsqrtf(fmaxf((float)cnt_src[i], 1.0f));

    __shared__ int sums[1024];
    const int CH = (NNODE + 1023) / 1024;  // 10
    int base = t * CH;
    int s = 0;
    for (int i = 0; i < CH; ++i) {
        int idx = base + i;
        if (idx < NNODE) s += cnt_dst[idx];
    }
    sums[t] = s;
    __syncthreads();
    for (int off = 1; off < 1024; off <<= 1) {
        int v = (t >= off) ? sums[t - off] : 0;
        __syncthreads();
        sums[t] += v;
        __syncthreads();
    }
    int run = (t == 0) ? 0 : sums[t - 1];
    for (int i = 0; i < CH; ++i) {
        int idx = base + i;
        if (idx < NNODE) { row_ptr[idx] = run; run += cnt_dst[idx]; }
    }
    if (t == 1023) row_ptr[NNODE] = sums[1023];
}

// ---------------------------------------------------------------------------
// 3. fill CSR (by dst)
// ---------------------------------------------------------------------------
__global__ void fill_kernel(const int* __restrict__ src, const int* __restrict__ dst,
                            int E, const int* __restrict__ row_ptr,
                            int* __restrict__ cursor, int* __restrict__ col) {
    int e = blockIdx.x * blockDim.x + threadIdx.x;
    if (e < E) {
        int v = dst[e];
        int pos = row_ptr[v] + atomicAdd(&cursor[v], 1);
        col[pos] = src[e];
    }
}

// ---------------------------------------------------------------------------
// 4. combine weights w_k
// ---------------------------------------------------------------------------
__global__ void w_kernel(const float* __restrict__ lam, float* __restrict__ w) {
    if (threadIdx.x == 0 && blockIdx.x == 0) {
        float c[5];
        float s0 = 1.0f / (1.0f + expf(-lam[0]));
        c[0] = s0;
        c[1] = s0;  // reference reuses lam[0] for all_h[1]
        c[2] = 1.0f / (1.0f + expf(-lam[1]));
        c[3] = 1.0f / (1.0f + expf(-lam[2]));
        c[4] = 1.0f / (1.0f + expf(-lam[3]));
        const float TH[5][5] = {
            {5.0f, -10.0f,  7.5f, -2.5f, 0.3125f},
            {0.0f,  10.0f, -15.0f, 7.5f, -1.25f },
            {0.0f,   0.0f,  7.5f, -7.5f, 1.875f },
            {0.0f,   0.0f,  0.0f,  2.5f, -1.25f },
            {0.0f,   0.0f,  0.0f,  0.0f, 0.3125f}};
        for (int k = 0; k < 5; ++k) {
            float acc = 0.0f;
            for (int i = 0; i < 5; ++i) acc += c[i] * TH[i][k];
            w[k] = acc;
        }
    }
}

// ---------------------------------------------------------------------------
// 4b. split in_feat (padded to PAD_M rows) into bf16 hi/lo
// ---------------------------------------------------------------------------
__global__ void split_in_kernel(const float* __restrict__ A,
                                unsigned short* __restrict__ Ahi,
                                unsigned short* __restrict__ Alo) {
    int i = blockIdx.x * blockDim.x + threadIdx.x;   // 4-element group
    size_t idx = (size_t)i * 4;
    if (idx >= (size_t)PAD_M * IND) return;
    int row = (int)(idx >> 9);
    ushortx4 hi = {0, 0, 0, 0}, lo = {0, 0, 0, 0};
    if (row < NNODE) {
        floatx4 v = *(const floatx4*)(A + idx);
#pragma unroll
        for (int c = 0; c < 4; ++c) {
            unsigned u = __float_as_uint(v[c]);
            float hif = __uint_as_float(u & 0xFFFF0000u);
            float lof = v[c] - hif;
            hi[c] = (unsigned short)(u >> 16);
            lo[c] = (unsigned short)(__float_as_uint(lof) >> 16);
        }
    }
    *(ushortx4*)(Ahi + idx) = hi;
    *(ushortx4*)(Alo + idx) = lo;
}

// ---------------------------------------------------------------------------
// 4c. split + transpose W -> WT [HD][IND] bf16 hi/lo
// ---------------------------------------------------------------------------
__global__ void split_wt_kernel(const float* __restrict__ W,
                                unsigned short* __restrict__ WThi,
                                unsigned short* __restrict__ WTlo) {
    int tid = blockIdx.x * blockDim.x + threadIdx.x;  // 0 .. IND*HD-1
    if (tid >= IND * HD) return;
    int n = tid & (HD - 1);
    int k = tid >> 8;
    float r = W[(size_t)k * HD + n];
    unsigned u = __float_as_uint(r);
    float hif = __uint_as_float(u & 0xFFFF0000u);
    float lof = r - hif;
    WThi[(size_t)n * IND + k] = (unsigned short)(u >> 16);
    WTlo[(size_t)n * IND + k] = (unsigned short)(__float_as_uint(lof) >> 16);
}

// ---------------------------------------------------------------------------
// 5. GEMM1 (MFMA, split-bf16): h = leaky_relu(in_feat @ W + b);
//    f_a = h; recons = w0 * h.  128x128 tile, grid (79, 2), 24 K-steps.
// ---------------------------------------------------------------------------
__global__ __launch_bounds__(256) void gemm1_mfma(
    const unsigned short* __restrict__ Ahi, const unsigned short* __restrict__ Alo,
    const unsigned short* __restrict__ WThi, const unsigned short* __restrict__ WTlo,
    const float* __restrict__ bias, const float* __restrict__ w5,
    float* __restrict__ h_out, float* __restrict__ recons) {
    __shared__ __align__(16) char smem[32768];
    unsigned short (*As)[64] = (unsigned short (*)[64])smem;
    unsigned short (*Bs)[64] = (unsigned short (*)[64])(smem + 16384);

    const int brow = blockIdx.x * 128, bcol = blockIdx.y * 128;
    const int t = threadIdx.x;
    const int lane = t & 63;
    const int wave = t >> 6;
    const int wm = wave >> 1, wn = wave & 1;
    const int fr = lane & 15;
    const int kq = lane >> 4;

    floatx4 acc[4][4];
#pragma unroll
    for (int i = 0; i < 4; ++i)
#pragma unroll
        for (int j = 0; j < 4; ++j)
            acc[i][j] = (floatx4){0.f, 0.f, 0.f, 0.f};

    const int srow = t >> 3;
    const int scol = (t & 7) * 8;

    for (int ks = 0; ks < 24; ++ks) {
        const int seg = ks >> 3;
        const int k0 = (ks & 7) * 64;
        const unsigned short* Aseg = (seg < 2) ? Ahi : Alo;
        const unsigned short* Bseg = (seg == 1) ? WTlo : WThi;
#pragma unroll
        for (int q = 0; q < 4; ++q) {
            const unsigned short* ga = Aseg + (size_t)(brow + q * 32 + srow) * IND + k0 + scol;
            const unsigned short* gb = Bseg + (size_t)(bcol + q * 32 + srow) * IND + k0 + scol;
            GLOAD_LDS16(ga, (unsigned short*)smem + q * 2048 + t * 8);
            GLOAD_LDS16(gb, (unsigned short*)smem + 8192 + q * 2048 + t * 8);
        }
        __syncthreads();
#pragma unroll
        for (int kk = 0; kk < 2; ++kk) {
            short8 a[4], b[4];
#pragma unroll
            for (int i = 0; i < 4; ++i)
                a[i] = *(const short8*)&As[wm * 64 + i * 16 + fr][kk * 32 + kq * 8];
#pragma unroll
            for (int j = 0; j < 4; ++j)
                b[j] = *(const short8*)&Bs[wn * 64 + j * 16 + fr][kk * 32 + kq * 8];
#pragma unroll
            for (int i = 0; i < 4; ++i)
#pragma unroll
                for (int j = 0; j < 4; ++j)
                    acc[i][j] = __builtin_amdgcn_mfma_f32_16x16x32_bf16(
                        a[i], b[j], acc[i][j], 0, 0, 0);
        }
        __syncthreads();
    }

    float w0 = w5[0];
#pragma unroll
    for (int i = 0; i < 4; ++i) {
#pragma unroll
        for (int j = 0; j < 4; ++j) {
            int gcol = bcol + wn * 64 + j * 16 + fr;   // < 256 always
            float bb = bias[gcol];
#pragma unroll
            for (int r = 0; r < 4; ++r) {
                int grow = brow + wm * 64 + i * 16 + kq * 4 + r;
                if (grow < NNODE) {
                    float v = acc[i][j][r] + bb;
                    v = v > 0.0f ? v : 0.01f * v;
                    h_out[(size_t)grow * HD + gcol] = v;
                    recons[(size_t)grow * HD + gcol] = w0 * v;
                }
            }
        }
    }
}

// ---------------------------------------------------------------------------
// 6. Laplacian step: 4 nodes/block, 64 lanes/node, float4 per lane (k = 1..3)
// ---------------------------------------------------------------------------
__global__ __launch_bounds__(256) void lap_kernel(
    const float* __restrict__ fin, float* __restrict__ fout,
    float* __restrict__ recons, const float* __restrict__ dinv,
    const int* __restrict__ row_ptr, const int* __restrict__ col,
    const float* __restrict__ w5, int k) {
    const int g = threadIdx.x >> 6;
    const int lane = threadIdx.x & 63;
    const int v = blockIdx.x * 4 + g;
    if (v >= NNODE) return;
    const float wk = w5[k];
    const int beg = row_ptr[v], end = row_ptr[v + 1];
    float s0 = 0.f, s1 = 0.f, s2 = 0.f, s3 = 0.f;
    const size_t coff = (size_t)lane * 4;
    for (int j = beg; j < end; ++j) {
        int u = col[j];
        float du = dinv[u];
        floatx4 fv = *(const floatx4*)(fin + (size_t)u * HD + coff);
        s0 = fmaf(fv[0], du, s0);
        s1 = fmaf(fv[1], du, s1);
        s2 = fmaf(fv[2], du, s2);
        s3 = fmaf(fv[3], du, s3);
    }
    const float dv = dinv[v];
    floatx4 fi = *(const floatx4*)(fin + (size_t)v * HD + coff);
    floatx4 o = {fi[0] - dv * s0, fi[1] - dv * s1, fi[2] - dv * s2, fi[3] - dv * s3};
    *(floatx4*)(fout + (size_t)v * HD + coff) = o;
    floatx4 rc = *(const floatx4*)(recons + (size_t)v * HD + coff);
    rc[0] = fmaf(wk, o[0], rc[0]);
    rc[1] = fmaf(wk, o[1], rc[1]);
    rc[2] = fmaf(wk, o[2], rc[2]);
    rc[3] = fmaf(wk, o[3], rc[3]);
    *(floatx4*)(recons + (size_t)v * HD + coff) = rc;
}

// ---------------------------------------------------------------------------
// 6b. last Laplacian step fused with bf16 hi/lo split of final recons
// ---------------------------------------------------------------------------
__global__ __launch_bounds__(256) void lap_last_kernel(
    const float* __restrict__ fin, const float* __restrict__ recons,
    const float* __restrict__ dinv,
    const int* __restrict__ row_ptr, const int* __restrict__ col,
    const float* __restrict__ w5,
    unsigned short* __restrict__ Rhi, unsigned short* __restrict__ Rlo) {
    const int g = threadIdx.x >> 6;
    const int lane = threadIdx.x & 63;
    const int v = blockIdx.x * 4 + g;
    if (v >= NNODE) return;
    const float w4 = w5[4];
    const int beg = row_ptr[v], end = row_ptr[v + 1];
    float s0 = 0.f, s1 = 0.f, s2 = 0.f, s3 = 0.f;
    const size_t coff = (size_t)lane * 4;
    for (int j = beg; j < end; ++j) {
        int u = col[j];
        float du = dinv[u];
        floatx4 fv = *(const floatx4*)(fin + (size_t)u * HD + coff);
        s0 = fmaf(fv[0], du, s0);
        s1 = fmaf(fv[1], du, s1);
        s2 = fmaf(fv[2], du, s2);
        s3 = fmaf(fv[3], du, s3);
    }
    const float dv = dinv[v];
    floatx4 fi = *(const floatx4*)(fin + (size_t)v * HD + coff);
    floatx4 rc = *(const floatx4*)(recons + (size_t)v * HD + coff);
    float ss[4] = {s0, s1, s2, s3};
    ushortx4 hi, lo;
#pragma unroll
    for (int c = 0; c < 4; ++c) {
        float o = fi[c] - dv * ss[c];
        float r = fmaf(w4, o, rc[c]);
        unsigned u = __float_as_uint(r);
        float hif = __uint_as_float(u & 0xFFFF0000u);
        float lof = r - hif;
        hi[c] = (unsigned short)(u >> 16);
        lo[c] = (unsigned short)(__float_as_uint(lof) >> 16);
    }
    *(ushortx4*)(Rhi + (size_t)v * HD + coff) = hi;
    *(ushortx4*)(Rlo + (size_t)v * HD + coff) = lo;
}

// ---------------------------------------------------------------------------
// 7. GEMM2 (MFMA): out = sigmoid(R R^T), lower-triangle + LDS-staged
//    full-line NT writes. XCD-swizzled block index (3160 = 8*395).
// ---------------------------------------------------------------------------
__global__ __launch_bounds__(256) void gemm2_mfma(
    const unsigned short* __restrict__ Rhi,
    const unsigned short* __restrict__ Rlo,
    float* __restrict__ out) {
    __shared__ __align__(16) char smem[32768];
    unsigned short (*As)[64] = (unsigned short (*)[64])smem;
    unsigned short (*Bs)[64] = (unsigned short (*)[64])(smem + 16384);

    // XCD-aware swizzle (bijective since NTRI % 8 == 0)
    int kb0 = blockIdx.x;
    int kb = (kb0 & 7) * (NTRI / 8) + (kb0 >> 3);
    // triangular decode: block kb -> (bi, bj), bi >= bj
    int bi = (int)((sqrtf(8.0f * (float)kb + 1.0f) - 1.0f) * 0.5f);
    while ((bi + 1) * (bi + 2) / 2 <= kb) ++bi;
    while (bi * (bi + 1) / 2 > kb) --bi;
    int bj = kb - bi * (bi + 1) / 2;
    const int brow = bi * 128, bcol = bj * 128;

    const int t = threadIdx.x;
    const int lane = t & 63;
    const int wave = t >> 6;
    const int wm = wave >> 1, wn = wave & 1;
    const int fr = lane & 15;
    const int kq = lane >> 4;

    floatx4 acc[4][4];
#pragma unroll
    for (int i = 0; i < 4; ++i)
#pragma unroll
        for (int j = 0; j < 4; ++j)
            acc[i][j] = (floatx4){0.f, 0.f, 0.f, 0.f};

    const int srow = t >> 3;
    const int scol = (t & 7) * 8;

    for (int ks = 0; ks < 12; ++ks) {
        const int seg = ks >> 2;
        const int k0 = (ks & 3) * 64;
        const unsigned short* Aseg = (seg < 2) ? Rhi : Rlo;
        const unsigned short* Bseg = (seg == 1) ? Rlo : Rhi;
#pragma unroll
        for (int q = 0; q < 4; ++q) {
            const unsigned short* ga = Aseg + (size_t)(brow + q * 32 + srow) * HD + k0 + scol;
            const unsigned short* gb = Bseg + (size_t)(bcol + q * 32 + srow) * HD + k0 + scol;
            GLOAD_LDS16(ga, (unsigned short*)smem + q * 2048 + t * 8);
            GLOAD_LDS16(gb, (unsigned short*)smem + 8192 + q * 2048 + t * 8);
        }
        __syncthreads();
#pragma unroll
        for (int kk = 0; kk < 2; ++kk) {
            short8 a[4], b[4];
#pragma unroll
            for (int i = 0; i < 4; ++i)
                a[i] = *(const short8*)&As[wm * 64 + i * 16 + fr][kk * 32 + kq * 8];
#pragma unroll
            for (int j = 0; j < 4; ++j)
                b[j] = *(const short8*)&Bs[wn * 64 + j * 16 + fr][kk * 32 + kq * 8];
#pragma unroll
            for (int i = 0; i < 4; ++i)
#pragma unroll
                for (int j = 0; j < 4; ++j)
                    acc[i][j] = __builtin_amdgcn_mfma_f32_16x16x32_bf16(
                        a[i], b[j], acc[i][j], 0, 0, 0);
        }
        __syncthreads();
    }

    const int tr = t >> 3, tl = t & 7;

    // --- direct tile: stage 32-row chunks in LDS, full-line NT writes ---
    {
        float (*sd)[132] = (float (*)[132])smem;
        const int cmaxd = NNODE - bcol;
#pragma unroll
        for (int c0 = 0; c0 < 128; c0 += 32) {
            if (wm == (c0 >> 6)) {
                int ibase = (c0 & 63) >> 4;
#pragma unroll
                for (int ii = 0; ii < 2; ++ii) {
                    int i = ibase + ii;
#pragma unroll
                    for (int j = 0; j < 4; ++j)
#pragma unroll
                        for (int r = 0; r < 4; ++r) {
                            float s = 1.0f / (1.0f + __expf(-acc[i][j][r]));
                            sd[ii * 16 + kq * 4 + r][wn * 64 + j * 16 + fr] = s;
                        }
                }
            }
            __syncthreads();
            int grow = brow + c0 + tr;
            if (grow < NNODE) {
                float* orow = out + (size_t)grow * NNODE + bcol;
#pragma unroll
                for (int k = 0; k < 4; ++k) {
                    int x = tl * 4 + k * 32;
                    if (x + 4 <= cmaxd) {
                        floatx4 v = {sd[tr][x], sd[tr][x + 1], sd[tr][x + 2], sd[tr][x + 3]};
                        __builtin_nontemporal_store(v, (floatx4*)(orow + x));
                    } else {
                        for (int xx = x; xx < cmaxd && xx < x + 4; ++xx)
                            __builtin_nontemporal_store(sd[tr][xx], orow + xx);
                    }
                }
            }
            __syncthreads();
        }
    }

    // --- mirror tile via LDS transpose (skip diagonal) ---
    if (bi == bj) return;
    {
        float (*trs)[129] = (float (*)[129])smem;
        const int cmax = NNODE - brow;
#pragma unroll
        for (int c0 = 0; c0 < 128; c0 += 32) {
            if (wn == (c0 >> 6)) {
                int jlo = (c0 & 63) >> 4;
#pragma unroll
                for (int jj = 0; jj < 2; ++jj) {
                    int j = jlo + jj;
#pragma unroll
                    for (int i = 0; i < 4; ++i)
#pragma unroll
                        for (int r = 0; r < 4; ++r) {
                            float s = 1.0f / (1.0f + __expf(-acc[i][j][r]));
                            trs[jj * 16 + fr][wm * 64 + i * 16 + kq * 4 + r] = s;
                        }
                }
            }
            __syncthreads();
            int gr = bcol + c0 + tr;
            float* orow = out + (size_t)gr * NNODE + brow;
#pragma unroll
            for (int k = 0; k < 4; ++k) {
                int x = tl * 4 + k * 32;
                if (x + 4 <= cmax) {
                    floatx4 v = {trs[tr][x], trs[tr][x + 1], trs[tr][x + 2], trs[tr][x + 3]};
                    __builtin_nontemporal_store(v, (floatx4*)(orow + x));
                } else {
                    for (int xx = x; xx < cmax && xx < x + 4; ++xx)
                        __builtin_nontemporal_store(trs[tr][xx], orow + xx);
                }
            }
            __syncthreads();
        }
    }
}

// ---------------------------------------------------------------------------
extern "C" void kernel_launch(void* const* d_in, const int* in_sizes, int n_in,
                              void* d_out, int out_size, void* d_ws, size_t ws_size,
                              hipStream_t stream) {
    const float* in_feat = (const float*)d_in[0];
    const float* W       = (const float*)d_in[1];
    const float* bias    = (const float*)d_in[2];
    const float* lam     = (const float*)d_in[3];
    const int*   src     = (const int*)d_in[4];
    const int*   dst     = (const int*)d_in[5];
    const int    E       = in_sizes[4];
    float* out = (float*)d_out;

    char* p = (char*)d_ws;
    auto alloc = [&](size_t bytes) -> void* {
        void* r = (void*)p;
        p += (bytes + 255) & ~(size_t)255;
        return r;
    };
    int*   cnts    = (int*)alloc(3 * NNODE * sizeof(int));
    int*   cnt_src = cnts;
    int*   cnt_dst = cnts + NNODE;
    int*   cursor  = cnts + 2 * NNODE;
    int*   row_ptr = (int*)alloc((NNODE + 1) * sizeof(int));
    int*   col     = (int*)alloc((size_t)E * sizeof(int));
    float* dinv    = (float*)alloc(NNODE * sizeof(float));
    float* w5      = (float*)alloc(8 * sizeof(float));
    float* f_a     = (float*)alloc((size_t)NNODE * HD * sizeof(float));
    float* f_b     = (float*)alloc((size_t)NNODE * HD * sizeof(float));
    float* recons  = (float*)alloc((size_t)NNODE * HD * sizeof(float));
    unsigned short* Rhi  = (unsigned short*)alloc((size_t)PAD_M * HD * sizeof(unsigned short));
    unsigned short* Rlo  = (unsigned short*)alloc((size_t)PAD_M * HD * sizeof(unsigned short));
    unsigned short* Ahi  = (unsigned short*)alloc((size_t)PAD_M * IND * sizeof(unsigned short));
    unsigned short* Alo  = (unsigned short*)alloc((size_t)PAD_M * IND * sizeof(unsigned short));
    unsigned short* WThi = (unsigned short*)alloc((size_t)HD * IND * sizeof(unsigned short));
    unsigned short* WTlo = (unsigned short*)alloc((size_t)HD * IND * sizeof(unsigned short));

    hipMemsetAsync(cnts, 0, 3 * NNODE * sizeof(int), stream);
    hipMemsetAsync(Rhi + (size_t)NNODE * HD, 0, (size_t)(PAD_M - NNODE) * HD * 2, stream);
    hipMemsetAsync(Rlo + (size_t)NNODE * HD, 0, (size_t)(PAD_M - NNODE) * HD * 2, stream);

    int eb = (E + 255) / 256;
    count_kernel<<<eb, 256, 0, stream>>>(src, dst, E, cnt_src, cnt_dst);
    w_kernel<<<1, 64, 0, stream>>>(lam, w5);
    scan_kernel<<<1, 1024, 0, stream>>>(cnt_src, cnt_dst, dinv, row_ptr);
    fill_kernel<<<eb, 256, 0, stream>>>(src, dst, E, row_ptr, cursor, col);

    // split inputs for MFMA gemm1
    int nsplit = (PAD_M * IND / 4 + 255) / 256;
    split_in_kernel<<<nsplit, 256, 0, stream>>>(in_feat, Ahi, Alo);
    split_wt_kernel<<<(IND * HD + 255) / 256, 256, 0, stream>>>(W, WThi, WTlo);

    dim3 g1(NTILE, HD / 128);
    gemm1_mfma<<<g1, 256, 0, stream>>>(Ahi, Alo, WThi, WTlo, bias, w5, f_a, recons);

    lap_kernel<<<NNODE / 4, 256, 0, stream>>>(f_a, f_b, recons, dinv, row_ptr, col, w5, 1);
    lap_kernel<<<NNODE / 4, 256, 0, stream>>>(f_b, f_a, recons, dinv, row_ptr, col, w5, 2);
    lap_kernel<<<NNODE / 4, 256, 0, stream>>>(f_a, f_b, recons, dinv, row_ptr, col, w5, 3);
    lap_last_kernel<<<NNODE / 4, 256, 0, stream>>>(f_b, recons, dinv, row_ptr, col, w5, Rhi, Rlo);

    gemm2_mfma<<<NTRI, 256, 0, stream>>>(Rhi, Rlo, out);
}